// Round 6
// baseline (273.725 us; speedup 1.0000x reference)
//
#include <hip/hip_runtime.h>
#include <math.h>

#define N 128
#define VOL (N*N*N)            // 2097152
#define PLANE (N*N)            // 16384
#define NKX 65                 // kept x-frequencies 0..64 (Hermitian half)
#define NSHELL 65              // shells 0..64
#define NREP 8                 // shell-bin replicas (split same-address atomics)
#define ACC_STRIDE 195         // 3*65 per batch

// packed complex: .x = re, .y = im. Vector ops lower to v_pk_*_f32.
typedef float cplx __attribute__((ext_vector_type(2)));

__device__ __forceinline__ int rev6(int x) { return (int)(__brev((unsigned)x) >> 26); }

// complex multiply by twiddle w=(c,s): r = a*c + swap(a)*(-s, s)
__device__ __forceinline__ cplx cmulw(cplx a, cplx w) {
    cplx sw = __builtin_shufflevector(a, a, 1, 0);
    return __builtin_elementwise_fma(sw, (cplx){-w.y, w.y}, a * w.x);
}

// ---- cross-lane exchange layer (VALU-pipe, no LDS except xor-4) ----
__device__ __forceinline__ void plswap32(cplx v, cplx& lo, cplx& hi) {
    float ax = v.x, bx = v.x, ay = v.y, by = v.y;
    asm("v_permlane32_swap_b32 %0, %1" : "+v"(ax), "+v"(bx));
    asm("v_permlane32_swap_b32 %0, %1" : "+v"(ay), "+v"(by));
    lo = (cplx){ax, ay}; hi = (cplx){bx, by};
}
__device__ __forceinline__ void plswap16(cplx v, cplx& lo, cplx& hi) {
    float ax = v.x, bx = v.x, ay = v.y, by = v.y;
    asm("v_permlane16_swap_b32 %0, %1" : "+v"(ax), "+v"(bx));
    asm("v_permlane16_swap_b32 %0, %1" : "+v"(ay), "+v"(by));
    lo = (cplx){ax, ay}; hi = (cplx){bx, by};
}
template<int CTRL>
__device__ __forceinline__ cplx dpp_xor(cplx v) {
    int rx = __builtin_amdgcn_mov_dpp(__float_as_int(v.x), CTRL, 0xF, 0xF, true);
    int ry = __builtin_amdgcn_mov_dpp(__float_as_int(v.y), CTRL, 0xF, 0xF, true);
    return (cplx){__int_as_float(rx), __int_as_float(ry)};
}
// h=4: no DPP/permlane pattern for xor4 -> single ds_swizzle on packed bf16
__device__ __forceinline__ cplx swz4(cplx v) {
    unsigned p = __builtin_amdgcn_perm(__float_as_uint(v.y), __float_as_uint(v.x), 0x07060302u);
    unsigned q = (unsigned)__builtin_amdgcn_ds_swizzle((int)p, 0x101F);  // xor 4
    return (cplx){__uint_as_float(q << 16), __uint_as_float(q & 0xFFFF0000u)};
}

// bf16x2 pack (RNE) / unpack: complex value in one uint (re low, im high)
__device__ __forceinline__ unsigned int pack_bf2(cplx v) {
    unsigned int r = __float_as_uint(v.x);
    unsigned int i = __float_as_uint(v.y);
    r = (r + 0x7FFFu + ((r >> 16) & 1u)) >> 16;
    i = (i + 0x7FFFu + ((i >> 16) & 1u)) & 0xFFFF0000u;
    return i | r;
}
__device__ __forceinline__ cplx unpack_bf2(unsigned int u) {
    return (cplx){__uint_as_float(u << 16), __uint_as_float(u & 0xFFFF0000u)};
}

// fp8 e4m3 packed complex pairs. Workspace word = {O:fp8x2 | T:fp8x2 << 16}.
__device__ __forceinline__ unsigned int pack_f8_pair(cplx O, cplx T) {
    int u = __builtin_amdgcn_cvt_pk_fp8_f32(O.x, O.y, 0, false);   // low 16
    u = __builtin_amdgcn_cvt_pk_fp8_f32(T.x, T.y, u, true);        // high 16
    return (unsigned int)u;
}
__device__ __forceinline__ cplx unpack_f8_lo(unsigned int u) {
    auto r = __builtin_amdgcn_cvt_pk_f32_fp8((int)u, false);
    return (cplx){r[0], r[1]};
}
__device__ __forceinline__ cplx unpack_f8_hi(unsigned int u) {
    auto r = __builtin_amdgcn_cvt_pk_f32_fp8((int)u, true);
    return (cplx){r[0], r[1]};
}
// fp8 e4m3 packed complex (re byte0, im byte1) for the in-LDS plane
__device__ __forceinline__ unsigned short pack_f8(cplx v) {
    int p = __builtin_amdgcn_cvt_pk_fp8_f32(v.x, v.y, 0, false);
    return (unsigned short)(p & 0xFFFF);
}
__device__ __forceinline__ cplx unpack_f8(unsigned short u) {
    auto r = __builtin_amdgcn_cvt_pk_f32_fp8((int)u, false);
    return (cplx){r[0], r[1]};
}

// 64-entry twiddle table W[m] = e^{-2*pi*i*m/128}, built once per block
__device__ __forceinline__ void build_W(cplx* Wsh, int tid) {
    if (tid < 64) {
        float s, c;
        sincosf(-6.283185307179586f * (float)tid / 128.0f, &s, &c);
        Wsh[tid] = (cplx){c, s};
    }
}

struct TwE { cplx w128; cplx we[5]; };

__device__ __forceinline__ TwE make_twe(const cplx* Wsh, int lane) {
    TwE w;
    w.w128 = Wsh[lane];
    #pragma unroll
    for (int i = 0; i < 5; i++) {
        int h = 32 >> i;
        cplx t = Wsh[(lane & (h - 1)) << (i + 1)];
        w.we[i] = (lane & h) ? t : (cplx){1.0f, 0.0f};
    }
    return w;
}

__device__ __forceinline__ void bstage(cplx& v, cplx o, float s, cplx we) {
    cplx t = __builtin_elementwise_fma((cplx){s, s}, v, o);
    v = cmulw(t, we);
}
__device__ __forceinline__ void bstage_lh(cplx& v, cplx lo, cplx hi, float s, cplx we) {
    cplx t = __builtin_elementwise_fma((cplx){s, s}, hi, lo);
    v = cmulw(t, we);
}

// Two independent 128-pt DIF FFTs (4 chains). 5 of 6 cross-lane stages on the
// VALU pipe (permlane_swap / DPP, fp32 exact); only xor-4 uses one ds_swizzle
// per complex (packed bf16). K=2 fixed: proven spill-free register footprint.
// Pair A: lane holds a0=x[lane], a1=x[lane+64]; same for pair B.
// Output: a0 = X[2*rev6(lane)], a1 = X[2*rev6(lane)+1].
__device__ __forceinline__ void fft128x2(cplx& a0, cplx& a1,
                                         cplx& b0, cplx& b1,
                                         const TwE& w, int lane) {
    cplx d;
    d  = a0 - a1;
    a0 = a0 + a1;
    a1 = cmulw(d, w.w128);
    d  = b0 - b1;
    b0 = b0 + b1;
    b1 = cmulw(d, w.w128);

    {   // h = 32 : permlane32_swap
        float s = (lane & 32) ? -1.0f : 1.0f;
        cplx l0, h0, l1, h1, l2, h2, l3, h3;
        plswap32(a0, l0, h0); plswap32(a1, l1, h1);
        plswap32(b0, l2, h2); plswap32(b1, l3, h3);
        bstage_lh(a0, l0, h0, s, w.we[0]);
        bstage_lh(a1, l1, h1, s, w.we[0]);
        bstage_lh(b0, l2, h2, s, w.we[0]);
        bstage_lh(b1, l3, h3, s, w.we[0]);
    }
    {   // h = 16 : permlane16_swap
        float s = (lane & 16) ? -1.0f : 1.0f;
        cplx l0, h0, l1, h1, l2, h2, l3, h3;
        plswap16(a0, l0, h0); plswap16(a1, l1, h1);
        plswap16(b0, l2, h2); plswap16(b1, l3, h3);
        bstage_lh(a0, l0, h0, s, w.we[1]);
        bstage_lh(a1, l1, h1, s, w.we[1]);
        bstage_lh(b0, l2, h2, s, w.we[1]);
        bstage_lh(b1, l3, h3, s, w.we[1]);
    }
    {   // h = 8 : DPP row_ror:8
        float s = (lane & 8) ? -1.0f : 1.0f;
        cplx o0 = dpp_xor<0x128>(a0), o1 = dpp_xor<0x128>(a1);
        cplx o2 = dpp_xor<0x128>(b0), o3 = dpp_xor<0x128>(b1);
        bstage(a0, o0, s, w.we[2]); bstage(a1, o1, s, w.we[2]);
        bstage(b0, o2, s, w.we[2]); bstage(b1, o3, s, w.we[2]);
    }
    {   // h = 4 : single LDS swizzle stage (packed bf16)
        float s = (lane & 4) ? -1.0f : 1.0f;
        cplx o0 = swz4(a0), o1 = swz4(a1), o2 = swz4(b0), o3 = swz4(b1);
        bstage(a0, o0, s, w.we[3]); bstage(a1, o1, s, w.we[3]);
        bstage(b0, o2, s, w.we[3]); bstage(b1, o3, s, w.we[3]);
    }
    {   // h = 2 : DPP quad_perm [2,3,0,1]
        float s = (lane & 2) ? -1.0f : 1.0f;
        cplx o0 = dpp_xor<0x4E>(a0), o1 = dpp_xor<0x4E>(a1);
        cplx o2 = dpp_xor<0x4E>(b0), o3 = dpp_xor<0x4E>(b1);
        bstage(a0, o0, s, w.we[4]); bstage(a1, o1, s, w.we[4]);
        bstage(b0, o2, s, w.we[4]); bstage(b1, o3, s, w.we[4]);
    }
    {   // h = 1 : DPP quad_perm [1,0,3,2], final butterfly (no twiddle)
        float s = (lane & 1) ? -1.0f : 1.0f;
        cplx o0 = dpp_xor<0xB1>(a0), o1 = dpp_xor<0xB1>(a1);
        cplx o2 = dpp_xor<0xB1>(b0), o3 = dpp_xor<0xB1>(b1);
        cplx sv = (cplx){s, s};
        a0 = __builtin_elementwise_fma(sv, a0, o0);
        a1 = __builtin_elementwise_fma(sv, a1, o1);
        b0 = __builtin_elementwise_fma(sv, b0, o2);
        b1 = __builtin_elementwise_fma(sv, b1, o3);
    }
}

// slot index holding frequency k after fft128
__device__ __forceinline__ int slot_of(int k) {
    return (k & 1) ? 64 + rev6(k >> 1) : rev6(k >> 1);
}

// ---- Pass 1: packed x-FFT (L = mo + i*tg), Hermitian unpack, keep kx=0..64 ----
// grid: nb*128(z) blocks of 1024 (16 waves, FULL 128-y plane per block; was
// 2 half-plane blocks -> halves the number of grid rounds). x-FFT results
// parked in LDS as bf16x2 (66KB tile -> 2 blocks/CU). Workspace element is
// u32 {O:fp8x2 | T:fp8x2<<16} at [b][kx][z][y]: HALF the interface bytes of
// round 5 (34 MB total ~ aggregate L2, so pass 2 re-reads mostly hit cache).
__global__ __launch_bounds__(1024, 8)
void fft_x_pack_kernel(const float* __restrict__ in0, const float* __restrict__ in1,
                       unsigned int* __restrict__ ws, int b0, float scale)
{
    __shared__ unsigned int tileL[128][129];   // bf16x2 L-values, 66048 B
    __shared__ cplx Wsh[64];
    int tid = threadIdx.x, lane = tid & 63, wave = tid >> 6;
    int bi = blockIdx.x;
    int z = bi & 127, b = bi >> 7;
    build_W(Wsh, tid);
    __syncthreads();
    TwE w = make_twe(Wsh, lane);

    size_t src_base = (size_t)(b0 + b) * VOL + (size_t)z * PLANE;
    #pragma unroll
    for (int r = 0; r < 8; r += 2) {
        int j0 = wave * 8 + r, j1 = j0 + 1;
        const float* pa0 = in0 + src_base + (size_t)j0 * N;
        const float* pa1 = in1 + src_base + (size_t)j0 * N;
        const float* pb0 = in0 + src_base + (size_t)j1 * N;
        const float* pb1 = in1 + src_base + (size_t)j1 * N;
        cplx a0 = (cplx){pa0[lane]      * scale, pa1[lane]      * scale};
        cplx a1 = (cplx){pa0[lane + 64] * scale, pa1[lane + 64] * scale};
        cplx c0 = (cplx){pb0[lane]      * scale, pb1[lane]      * scale};
        cplx c1 = (cplx){pb0[lane + 64] * scale, pb1[lane + 64] * scale};
        fft128x2(a0, a1, c0, c1, w, lane);
        tileL[j0][lane]      = pack_bf2(a0);
        tileL[j0][lane + 64] = pack_bf2(a1);
        tileL[j1][lane]      = pack_bf2(c0);
        tileL[j1][lane + 64] = pack_bf2(c1);
    }
    __syncthreads();

    // unpack: O = (L(k)+conj(L(-k)))/2 ; T = (L(k)-conj(L(-k)))/(2i)
    // j spans 128 consecutive y per kx (wave-uniform kx) -> 256B store runs.
    size_t dst_off = (size_t)b * NKX * PLANE + (size_t)z * N;
    for (int idx = tid; idx < NKX * 128; idx += 1024) {
        int j  = idx & 127;
        int kx = idx >> 7;               // wave-uniform (64-lane waves in 128 groups)
        int mk = (128 - kx) & 127;
        cplx a  = unpack_bf2(tileL[j][slot_of(kx)]);
        cplx bm = unpack_bf2(tileL[j][slot_of(mk)]);
        cplx O = (cplx){0.5f * (a.x + bm.x), 0.5f * (a.y - bm.y)};
        cplx T = (cplx){0.5f * (a.y + bm.y), 0.5f * (bm.x - a.x)};
        ws[dst_off + (size_t)kx * PLANE + j] = pack_f8_pair(O, T);
    }
}

// ---- Fused pass 2: y-FFT + z-FFT + shell accumulation per (b, kx) plane ----
// grid: nb*64 blocks of 1024 (16 waves); 2 blocks/CU * 256 CUs at nb=8 -> no
// tail. Complementary plane pairing: kslot<32 -> kx=kslot (heavy planes),
// kslot 33..63 -> kx=95-kslot (light planes), kslot 32 -> kx=63 AND 64.
// Shell bins 8-way replicated (replica = rev6(lane)&7).
// Phase A reads ONE u32 {O,T} per point (half of round 5's bytes).
// LDS plane as fp8x2; amplitude pre-scale x64 from pass 1 -> shell sums
// x4096, undone at flush. Swizzle col = (z + ky) & 127.
__global__ __launch_bounds__(1024, 8)
void fft_yz_acc_kernel(const unsigned int* __restrict__ ws, float* __restrict__ gacc,
                       int nb, int b0)
{
    __shared__ unsigned short tile[2][128][128];   // 65536 B
    __shared__ cplx Wsh[64];
    __shared__ float accn[NREP][NSHELL], accp[NREP][NSHELL], accq[NREP][NSHELL];
    int tid = threadIdx.x, lane = tid & 63, wave = tid >> 6;
    int bi = blockIdx.x;
    int kslot = bi / nb;              // 0..63
    int b = bi - kslot * nb;
    int np = (kslot == 32) ? 2 : 1;
    int kxbase = (kslot < 32) ? kslot : (95 - kslot);   // kslot 32 -> 63 (+p)

    build_W(Wsh, tid);
    __syncthreads();
    TwE w = make_twe(Wsh, lane);

    int m6  = rev6(lane);
    int rep = m6 & (NREP - 1);
    int kz0 = 2 * m6, kz1 = kz0 + 1;
    int cz0 = (kz0 < 64) ? kz0 : kz0 - 128;
    int cz1 = (kz1 < 64) ? kz1 : kz1 - 128;
    int z20 = cz0 * cz0, z21 = cz1 * cz1;

    for (int p = 0; p < np; p++) {
        int kx = kxbase + p;
        {   // zero the replicated bins
            float* an = &accn[0][0];
            float* ap = &accp[0][0];
            float* aq = &accq[0][0];
            for (int i = tid; i < NREP * NSHELL; i += 1024) { an[i] = 0.0f; ap[i] = 0.0f; aq[i] = 0.0f; }
        }
        __syncthreads();

        // Phase A: 128 z-lines, each u32 carrying {O,T}; wave handles 8,
        // one-step register prefetch to hide the memory latency under the FFT.
        const unsigned int* pz = ws + ((size_t)b * NKX + kx) * PLANE + (size_t)(wave * 8) * N;
        unsigned int v0 = pz[lane];
        unsigned int v1 = pz[lane + 64];
        for (int c = 0; c < 8; c++) {
            unsigned int n0 = 0, n1 = 0;
            if (c < 7) {   // prefetch next line (wave-uniform branch)
                n0 = pz[(size_t)(c + 1) * N + lane];
                n1 = pz[(size_t)(c + 1) * N + lane + 64];
            }
            cplx a0 = unpack_f8_lo(v0);
            cplx a1 = unpack_f8_lo(v1);
            cplx t0 = unpack_f8_hi(v0);
            cplx t1 = unpack_f8_hi(v1);
            fft128x2(a0, a1, t0, t1, w, lane);
            int z0 = wave * 8 + c;
            int ky0 = 2 * m6;                        // a1/t1 hold ky0+1
            tile[0][ky0    ][(z0 + ky0    ) & 127] = pack_f8(a0);
            tile[0][ky0 + 1][(z0 + ky0 + 1) & 127] = pack_f8(a1);
            tile[1][ky0    ][(z0 + ky0    ) & 127] = pack_f8(t0);
            tile[1][ky0 + 1][(z0 + ky0 + 1) & 127] = pack_f8(t1);
            v0 = n0; v1 = n1;
        }
        __syncthreads();

        // Phase B: z-FFT per live ky line (o and t interleaved) + accumulate
        int kx2 = kx * kx;
        for (int c = 0; c < 8; c++) {
            int ky = wave + 16 * c;
            int cy = (ky < 64) ? ky : ky - 128;
            int base2 = kx2 + cy * cy;
            if (base2 > 4224) continue;              // whole z-line outside sphere
            int c0 = (lane + ky) & 127;
            int c1 = (lane + 64 + ky) & 127;
            cplx o0 = unpack_f8(tile[0][ky][c0]);
            cplx o1 = unpack_f8(tile[0][ky][c1]);
            cplx t0 = unpack_f8(tile[1][ky][c0]);
            cplx t1 = unpack_f8(tile[1][ky][c1]);
            fft128x2(o0, o1, t0, t1, w, lane);
            int r20 = base2 + z20;
            if (r20 <= 4224) {
                int sh = (int)sqrtf((float)r20);
                if ((sh + 1) * (sh + 1) <= r20) sh++;
                else if (sh * sh > r20) sh--;
                atomicAdd(&accn[rep][sh], o0.x * t0.x + o0.y * t0.y);
                atomicAdd(&accp[rep][sh], o0.x * o0.x + o0.y * o0.y);
                atomicAdd(&accq[rep][sh], t0.x * t0.x + t0.y * t0.y);
            }
            int r21 = base2 + z21;
            if (r21 <= 4224) {
                int sh = (int)sqrtf((float)r21);
                if ((sh + 1) * (sh + 1) <= r21) sh++;
                else if (sh * sh > r21) sh--;
                atomicAdd(&accn[rep][sh], o1.x * t1.x + o1.y * t1.y);
                atomicAdd(&accp[rep][sh], o1.x * o1.x + o1.y * o1.y);
                atomicAdd(&accq[rep][sh], t1.x * t1.x + t1.y * t1.y);
            }
        }
        __syncthreads();

        if (tid < NSHELL) {
            float sn = 0.0f, sp = 0.0f, sq = 0.0f;
            #pragma unroll
            for (int r = 0; r < NREP; r++) { sn += accn[r][tid]; sp += accp[r][tid]; sq += accq[r][tid]; }
            // Hermitian mirror weight * 1/4096 (undo the x64 amplitude pre-scale)
            float wgt = ((kx == 0 || kx == 64) ? 1.0f : 2.0f) * (1.0f / 4096.0f);
            float* g = gacc + (size_t)(b0 + b) * ACC_STRIDE;
            atomicAdd(&g[tid],              wgt * sn);
            atomicAdd(&g[NSHELL + tid],     wgt * sp);
            atomicAdd(&g[2 * NSHELL + tid], wgt * sq);
        }
        if (p + 1 < np) __syncthreads();   // protect bin re-zero + tile reuse
    }
}

// ---------------- Finalize: fsc -> loss scalar -----------------------------
__global__ void finalize_kernel(const float* __restrict__ gacc,
                                float* __restrict__ out)
{
    int lane = threadIdx.x;   // 64 threads, shell = lane+1 (1..64)
    int sh = lane + 1;
    float total = 0.0f;
    #pragma unroll
    for (int b = 0; b < 8; b++) {
        const float* g = gacc + b * ACC_STRIDE;
        float num = g[sh];
        float po  = g[NSHELL + sh];
        float pt  = g[2 * NSHELL + sh];
        float fsc = num / sqrtf(po * pt + 1e-6f);
        fsc = fminf(1.0f, fmaxf(-1.0f, fsc));
        total += fsc;
    }
    #pragma unroll
    for (int off = 32; off; off >>= 1) total += __shfl_down(total, off);
    if (lane == 0) out[0] = 1.0f - total / (64.0f * 8.0f);
}

extern "C" void kernel_launch(void* const* d_in, const int* in_sizes, int n_in,
                              void* d_out, int out_size, void* d_ws, size_t ws_size,
                              hipStream_t stream) {
    const float* in0 = (const float*)d_in[0];   // model_output (8,1,128,128,128)
    const float* in1 = (const float*)d_in[1];   // target
    float* gacc = (float*)d_ws;                 // 8*195 floats
    unsigned int* wsA = (unsigned int*)((char*)d_ws + 8192);

    hipMemsetAsync(d_ws, 0, 8 * ACC_STRIDE * sizeof(float), stream);

    size_t avail = (ws_size > 8192) ? ws_size - 8192 : 0;
    size_t per_batch = (size_t)NKX * PLANE * sizeof(unsigned int);   // ~4.3 MB
    int NB = (int)(avail / per_batch);
    if (NB > 8) NB = 8;
    if (NB < 1) NB = 1;

    // 64 / sqrt(128^3): ortho norm plus x64 amplitude pre-scale so both the
    // fp8 workspace (post-x std ~0.5) and the fp8 LDS plane (post-y std ~5.7)
    // sit in e4m3's normal range; shell sums are x4096, undone at flush.
    const float scale = 4.4194173824159216e-2f;

    for (int b0 = 0; b0 < 8; b0 += NB) {
        int nb = (8 - b0 < NB) ? (8 - b0) : NB;
        fft_x_pack_kernel<<<dim3(nb * 128), dim3(1024), 0, stream>>>(in0, in1, wsA, b0, scale);
        fft_yz_acc_kernel<<<dim3(nb * 64), dim3(1024), 0, stream>>>(wsA, gacc, nb, b0);
    }
    finalize_kernel<<<dim3(1), dim3(64), 0, stream>>>(gacc, (float*)d_out);
}